// Round 8
// baseline (167.917 us; speedup 1.0000x reference)
//
#include <hip/hip_runtime.h>
#include <hip/hip_bf16.h>

// out[e,i] = sum_j (e@W1+b1)[e, i*16+j] * h[e,j]  +  (e@W2+b2)[e,i]
// One fp16 MFMA GEMM over K=576 per 16-edge tile (18x mfma_f32_16x16x32_f16).
// K-mapping (same placement function on A and B sides):
//   main block kk=0..15, slot s=(lane>>4)*8+t:  (d=s, j=kk)
//     A[r,s] = e[edge_r, s] * h[edge_r, kk]     B[s, i=r] = W1[s*256 + r*16 + kk]
//   block 16: A = e[edge, s],                   B = W2[s*16 + r]
//   block 17: s<16: A=h[edge,s], B=b1[r*16+s]; s==16: A=1, B=b2[r]; else 0
// R7: (1) rotating 4-deep B-frag preload decouples ds_read latency from MFMA;
//     (2) u32 byte-offset incremental addressing (v_add+v_min per ptr per tile);
//     (3) B-build parallel across 4 waves; (4) launch_bounds(256,4) pins <=128 VGPR.
// NO local arrays (R2 PromoteAlloca lesson). No inline asm.

using f16x8  = __attribute__((ext_vector_type(8))) _Float16;
using f16x2  = __attribute__((ext_vector_type(2))) _Float16;
using fp16v2 = __attribute__((ext_vector_type(2))) __fp16;   // native cvt_pkrtz type
using f32x4  = __attribute__((ext_vector_type(4))) float;
using u32x4  = __attribute__((ext_vector_type(4))) unsigned int;

static __device__ __forceinline__ unsigned int pkrtz(float lo, float hi) {
    fp16v2 p = __builtin_amdgcn_cvt_pkrtz(lo, hi);
    return __builtin_bit_cast(unsigned int, p);
}
static __device__ __forceinline__ f16x2 u2h(unsigned int u) {
    return __builtin_bit_cast(f16x2, u);
}
static __device__ __forceinline__ unsigned int h2u(f16x2 h) {
    return __builtin_bit_cast(unsigned int, h);
}
static __device__ __forceinline__ unsigned short f2h_bits(float x) {
    _Float16 h = (_Float16)x;                 // RNE scalar cast (one-time build only)
    return __builtin_bit_cast(unsigned short, h);
}

__global__ void __launch_bounds__(256, 4) msg_kernel(
    const float* __restrict__ hptr, const float* __restrict__ eptr,
    const float* __restrict__ W1,   const float* __restrict__ b1,
    const float* __restrict__ W2,   const float* __restrict__ b2,
    float* __restrict__ out, int E)
{
    // B fragment store: [kk=0..17][lane=0..63][t=0..7] fp16, 18 KB.
    __shared__ __align__(16) unsigned short Bs[18 * 64 * 8];

    const int lane = threadIdx.x & 63;
    const int g    = lane >> 4;        // K-group (0..3); lane's d-range = [g*8, g*8+8)
    const int r    = lane & 15;        // A row (edge-in-tile) == B/D col (output i)
    const int wv   = threadIdx.x >> 6; // wave in block: parallel B-build by t-pair

    // ---- build B in LDS: wave wv handles t = wv*2, wv*2+1 ----
    #pragma unroll
    for (int tq = 0; tq < 2; ++tq) {
        const int t = wv * 2 + tq;
        const int d = g * 8 + t;
        const float4* wp = (const float4*)(W1 + (size_t)d * 256 + r * 16);
        const float4 w0 = wp[0], w1 = wp[1], w2 = wp[2], w3 = wp[3];
        Bs[( 0*64 + lane)*8 + t] = f2h_bits(w0.x);
        Bs[( 1*64 + lane)*8 + t] = f2h_bits(w0.y);
        Bs[( 2*64 + lane)*8 + t] = f2h_bits(w0.z);
        Bs[( 3*64 + lane)*8 + t] = f2h_bits(w0.w);
        Bs[( 4*64 + lane)*8 + t] = f2h_bits(w1.x);
        Bs[( 5*64 + lane)*8 + t] = f2h_bits(w1.y);
        Bs[( 6*64 + lane)*8 + t] = f2h_bits(w1.z);
        Bs[( 7*64 + lane)*8 + t] = f2h_bits(w1.w);
        Bs[( 8*64 + lane)*8 + t] = f2h_bits(w2.x);
        Bs[( 9*64 + lane)*8 + t] = f2h_bits(w2.y);
        Bs[(10*64 + lane)*8 + t] = f2h_bits(w2.z);
        Bs[(11*64 + lane)*8 + t] = f2h_bits(w2.w);
        Bs[(12*64 + lane)*8 + t] = f2h_bits(w3.x);
        Bs[(13*64 + lane)*8 + t] = f2h_bits(w3.y);
        Bs[(14*64 + lane)*8 + t] = f2h_bits(w3.z);
        Bs[(15*64 + lane)*8 + t] = f2h_bits(w3.w);
        Bs[(16*64 + lane)*8 + t] = f2h_bits(W2[d * 16 + r]);
        float v;
        if (d < 16)       v = b1[r * 16 + d];
        else if (d == 16) v = b2[r];
        else              v = 0.0f;
        Bs[(17*64 + lane)*8 + t] = f2h_bits(v);
    }
    __syncthreads();   // only barrier in the kernel

    const int ntiles = (E + 15) >> 4;
    const int nwaves = (gridDim.x * blockDim.x) >> 6;
    const int wid    = (blockIdx.x * blockDim.x + threadIdx.x) >> 6;
    if (wid >= ntiles) return;

    const unsigned short* bsl = &Bs[lane * 8];   // per-lane base; block kk at +kk*512

    // u32 incremental byte offsets (arrays are <256 MB, fits u32)
    const unsigned int offEmax = (unsigned int)(E - 1) * 128u + (unsigned int)g * 32u;
    const unsigned int offHmax = (unsigned int)(E - 1) * 64u;
    const unsigned int stepE = (unsigned int)(2 * nwaves) * 2048u;  // per-stage tile step
    const unsigned int stepH = (unsigned int)(2 * nwaves) * 1024u;
    const unsigned int stepO = (unsigned int)(2 * nwaves) * 1024u;

    int tA = wid, tB = wid + nwaves;
    unsigned int offEA, offHA, offOA, offEB, offHB, offOB;
    {
        int ta = tA < ntiles ? tA : ntiles - 1;
        int ca = ta * 16 + r; if (ca > E - 1) ca = E - 1;
        offEA = (unsigned int)ca * 128u + (unsigned int)g * 32u;
        offHA = (unsigned int)ca * 64u;
        offOA = (unsigned int)(ta * 16 + g * 4) * 64u + (unsigned int)r * 4u;
        int tb = tB < ntiles ? tB : ntiles - 1;
        int cb = tb * 16 + r; if (cb > E - 1) cb = E - 1;
        offEB = (unsigned int)cb * 128u + (unsigned int)g * 32u;
        offHB = (unsigned int)cb * 64u;
        offOB = (unsigned int)(tb * 16 + g * 4) * 64u + (unsigned int)r * 4u;
    }

#define LDSB(KK) __builtin_bit_cast(f16x8, *reinterpret_cast<const u32x4*>(bsl + (KK) * 512))

#define LOADS(OE, OH, E0, E1, H0, H1, H2, H3) { \
        const float4* ep_ = (const float4*)((const char*)eptr + (OE)); \
        E0 = ep_[0]; E1 = ep_[1]; \
        const float4* hp_ = (const float4*)((const char*)hptr + (OH)); \
        H0 = hp_[0]; H1 = hp_[1]; H2 = hp_[2]; H3 = hp_[3]; }

#define MB(HB, BF, ACC) { \
        const f16x2 hh_ = u2h(HB); \
        u32x4 u_ = {h2u(hh_ * u2h(eP0)), h2u(hh_ * u2h(eP1)), \
                    h2u(hh_ * u2h(eP2)), h2u(hh_ * u2h(eP3))}; \
        ACC = __builtin_amdgcn_mfma_f32_16x16x32_f16( \
            __builtin_bit_cast(f16x8, u_), BF, ACC, 0, 0, 0); }

    // BODY: Fb preload -> convert -> advance+prefetch -> 18 MFMAs (rotated B) -> store
#define BODY(TV, OE, OH, OO, E0, E1, H0, H1, H2, H3) { \
        f16x8 Fb0 = LDSB(0), Fb1 = LDSB(1), Fb2 = LDSB(2), Fb3 = LDSB(3); \
        const unsigned int eP0 = pkrtz(E0.x, E0.y), eP1 = pkrtz(E0.z, E0.w); \
        const unsigned int eP2 = pkrtz(E1.x, E1.y), eP3 = pkrtz(E1.z, E1.w); \
        const unsigned int hB0  = pkrtz(H0.x, H0.x), hB1  = pkrtz(H0.y, H0.y); \
        const unsigned int hB2  = pkrtz(H0.z, H0.z), hB3  = pkrtz(H0.w, H0.w); \
        const unsigned int hB4  = pkrtz(H1.x, H1.x), hB5  = pkrtz(H1.y, H1.y); \
        const unsigned int hB6  = pkrtz(H1.z, H1.z), hB7  = pkrtz(H1.w, H1.w); \
        const unsigned int hB8  = pkrtz(H2.x, H2.x), hB9  = pkrtz(H2.y, H2.y); \
        const unsigned int hB10 = pkrtz(H2.z, H2.z), hB11 = pkrtz(H2.w, H2.w); \
        const unsigned int hB12 = pkrtz(H3.x, H3.x), hB13 = pkrtz(H3.y, H3.y); \
        const unsigned int hB14 = pkrtz(H3.z, H3.z), hB15 = pkrtz(H3.w, H3.w); \
        const float v0_ = (g == 0) ? H0.x : (g == 1) ? H2.x : (g == 2) ? 1.0f : 0.0f; \
        const float v1_ = (g == 0) ? H0.y : (g == 1) ? H2.y : 0.0f; \
        const float v2_ = (g == 0) ? H0.z : (g == 1) ? H2.z : 0.0f; \
        const float v3_ = (g == 0) ? H0.w : (g == 1) ? H2.w : 0.0f; \
        const float v4_ = (g == 0) ? H1.x : (g == 1) ? H3.x : 0.0f; \
        const float v5_ = (g == 0) ? H1.y : (g == 1) ? H3.y : 0.0f; \
        const float v6_ = (g == 0) ? H1.z : (g == 1) ? H3.z : 0.0f; \
        const float v7_ = (g == 0) ? H1.w : (g == 1) ? H3.w : 0.0f; \
        const unsigned int a17_0 = pkrtz(v0_, v1_), a17_1 = pkrtz(v2_, v3_); \
        const unsigned int a17_2 = pkrtz(v4_, v5_), a17_3 = pkrtz(v6_, v7_); \
        OE = min(OE + stepE, offEmax); \
        OH = min(OH + stepH, offHmax); \
        LOADS(OE, OH, E0, E1, H0, H1, H2, H3); \
        f32x4 acc0 = {0.0f, 0.0f, 0.0f, 0.0f}; \
        f32x4 acc1 = {0.0f, 0.0f, 0.0f, 0.0f}; \
        MB(hB0,  Fb0, acc0)  Fb0 = LDSB( 4); \
        MB(hB1,  Fb1, acc1)  Fb1 = LDSB( 5); \
        MB(hB2,  Fb2, acc0)  Fb2 = LDSB( 6); \
        MB(hB3,  Fb3, acc1)  Fb3 = LDSB( 7); \
        MB(hB4,  Fb0, acc0)  Fb0 = LDSB( 8); \
        MB(hB5,  Fb1, acc1)  Fb1 = LDSB( 9); \
        MB(hB6,  Fb2, acc0)  Fb2 = LDSB(10); \
        MB(hB7,  Fb3, acc1)  Fb3 = LDSB(11); \
        MB(hB8,  Fb0, acc0)  Fb0 = LDSB(12); \
        MB(hB9,  Fb1, acc1)  Fb1 = LDSB(13); \
        MB(hB10, Fb2, acc0)  Fb2 = LDSB(14); \
        MB(hB11, Fb3, acc1)  Fb3 = LDSB(15); \
        MB(hB12, Fb0, acc0)  Fb0 = LDSB(16); \
        MB(hB13, Fb1, acc1)  Fb1 = LDSB(17); \
        MB(hB14, Fb2, acc0) \
        MB(hB15, Fb3, acc1) \
        {   u32x4 u_ = {eP0, eP1, eP2, eP3};     /* block 16: A = e */ \
            acc0 = __builtin_amdgcn_mfma_f32_16x16x32_f16( \
                __builtin_bit_cast(f16x8, u_), Fb0, acc0, 0, 0, 0); } \
        {   u32x4 u_ = {a17_0, a17_1, a17_2, a17_3};  /* block 17 */ \
            acc1 = __builtin_amdgcn_mfma_f32_16x16x32_f16( \
                __builtin_bit_cast(f16x8, u_), Fb1, acc1, 0, 0, 0); } \
        float* op_ = (float*)((char*)out + (OO)); \
        const int rowbase_ = (TV) * 16 + g * 4; \
        const float s0_ = acc0[0] + acc1[0], s1_ = acc0[1] + acc1[1]; \
        const float s2_ = acc0[2] + acc1[2], s3_ = acc0[3] + acc1[3]; \
        if (rowbase_ + 3 < E) { op_[0] = s0_; op_[16] = s1_; op_[32] = s2_; op_[48] = s3_; } \
        else { \
            if (rowbase_     < E) op_[ 0] = s0_; \
            if (rowbase_ + 1 < E) op_[16] = s1_; \
            if (rowbase_ + 2 < E) op_[32] = s2_; \
        } \
        OO += stepO; \
        TV += 2 * nwaves; }

    // ---- 2-deep pipeline, stages A/B alternate ----
    float4 aE0, aE1, aH0, aH1, aH2, aH3;
    float4 bE0, bE1, bH0, bH1, bH2, bH3;
    LOADS(offEA, offHA, aE0, aE1, aH0, aH1, aH2, aH3);
    LOADS(offEB, offHB, bE0, bE1, bH0, bH1, bH2, bH3);

    while (true) {
        BODY(tA, offEA, offHA, offOA, aE0, aE1, aH0, aH1, aH2, aH3);
        if (tB >= ntiles) break;
        BODY(tB, offEB, offHB, offOB, bE0, bE1, bH0, bH1, bH2, bH3);
        if (tA >= ntiles) break;
    }

#undef BODY
#undef MB
#undef LOADS
#undef LDSB
}

extern "C" void kernel_launch(void* const* d_in, const int* in_sizes, int n_in,
                              void* d_out, int out_size, void* d_ws, size_t ws_size,
                              hipStream_t stream) {
    const float* h  = (const float*)d_in[0];
    const float* e  = (const float*)d_in[1];
    const float* W1 = (const float*)d_in[2];
    const float* b1 = (const float*)d_in[3];
    const float* W2 = (const float*)d_in[4];
    const float* b2 = (const float*)d_in[5];
    float* out = (float*)d_out;

    const int E = in_sizes[0] / 16;   // h is [E,16]

    dim3 grid(2048), block(256);
    hipLaunchKernelGGL(msg_kernel, grid, block, 0, stream,
                       h, e, W1, b1, W2, b2, out, E);
}

// Round 9
// 91.606 us; speedup vs baseline: 1.8330x; 1.8330x over previous
//
#include <hip/hip_runtime.h>
#include <hip/hip_bf16.h>

// out[e,i] = sum_j (e@W1+b1)[e, i*16+j] * h[e,j]  +  (e@W2+b2)[e,i]
// One fp16 MFMA GEMM over K=576 per 16-edge tile (18x mfma_f32_16x16x32_f16).
// K-mapping (same placement function on A and B sides):
//   main block kk=0..15, slot s=(lane>>4)*8+t:  (d=s, j=kk)
//     A[r,s] = e[edge_r, s] * h[edge_r, kk]     B[s, i=r] = W1[s*256 + r*16 + kk]
//   block 16: A = e[edge, s],                   B = W2[s*16 + r]
//   block 17: s<16: A=h[edge,s], B=b1[r*16+s]; s==16: A=1, B=b2[r]; else 0
// R8 = R6 structure (84 VGPR, no spills) + rotating 4-reg B-frag preload
// (ds_read issued 4 MFMAs ahead of use) + 4-wave-parallel B build + fast-path
// store. NO launch_bounds min-waves (R7: allocator spilled pipeline to scratch,
// FETCH 150->397MB). NO local arrays (R2 PromoteAlloca lesson).

using f16x8  = __attribute__((ext_vector_type(8))) _Float16;
using f16x2  = __attribute__((ext_vector_type(2))) _Float16;
using fp16v2 = __attribute__((ext_vector_type(2))) __fp16;   // native cvt_pkrtz type
using f32x4  = __attribute__((ext_vector_type(4))) float;
using u32x4  = __attribute__((ext_vector_type(4))) unsigned int;

static __device__ __forceinline__ unsigned int pkrtz(float lo, float hi) {
    fp16v2 p = __builtin_amdgcn_cvt_pkrtz(lo, hi);
    return __builtin_bit_cast(unsigned int, p);
}
static __device__ __forceinline__ f16x2 u2h(unsigned int u) {
    return __builtin_bit_cast(f16x2, u);
}
static __device__ __forceinline__ unsigned int h2u(f16x2 h) {
    return __builtin_bit_cast(unsigned int, h);
}
static __device__ __forceinline__ unsigned short f2h_bits(float x) {
    _Float16 h = (_Float16)x;                 // RNE scalar cast (one-time build only)
    return __builtin_bit_cast(unsigned short, h);
}

__global__ void __launch_bounds__(256) msg_kernel(
    const float* __restrict__ hptr, const float* __restrict__ eptr,
    const float* __restrict__ W1,   const float* __restrict__ b1,
    const float* __restrict__ W2,   const float* __restrict__ b2,
    float* __restrict__ out, int E)
{
    // B fragment store: [kk=0..17][lane=0..63][t=0..7] fp16, 18 KB.
    __shared__ __align__(16) unsigned short Bs[18 * 64 * 8];

    const int lane = threadIdx.x & 63;
    const int g    = lane >> 4;        // K-group (0..3); lane's d-range = [g*8, g*8+8)
    const int r    = lane & 15;        // A row (edge-in-tile) == B/D col (output i)
    const int wv   = threadIdx.x >> 6; // wave id: parallel B-build by t-pair

    // ---- build B in LDS: wave wv handles t = wv*2, wv*2+1 ----
    #pragma unroll
    for (int tq = 0; tq < 2; ++tq) {
        const int t = wv * 2 + tq;
        const int d = g * 8 + t;
        const float4* wp = (const float4*)(W1 + (size_t)d * 256 + r * 16);
        const float4 w0 = wp[0], w1 = wp[1], w2 = wp[2], w3 = wp[3];
        Bs[( 0*64 + lane)*8 + t] = f2h_bits(w0.x);
        Bs[( 1*64 + lane)*8 + t] = f2h_bits(w0.y);
        Bs[( 2*64 + lane)*8 + t] = f2h_bits(w0.z);
        Bs[( 3*64 + lane)*8 + t] = f2h_bits(w0.w);
        Bs[( 4*64 + lane)*8 + t] = f2h_bits(w1.x);
        Bs[( 5*64 + lane)*8 + t] = f2h_bits(w1.y);
        Bs[( 6*64 + lane)*8 + t] = f2h_bits(w1.z);
        Bs[( 7*64 + lane)*8 + t] = f2h_bits(w1.w);
        Bs[( 8*64 + lane)*8 + t] = f2h_bits(w2.x);
        Bs[( 9*64 + lane)*8 + t] = f2h_bits(w2.y);
        Bs[(10*64 + lane)*8 + t] = f2h_bits(w2.z);
        Bs[(11*64 + lane)*8 + t] = f2h_bits(w2.w);
        Bs[(12*64 + lane)*8 + t] = f2h_bits(w3.x);
        Bs[(13*64 + lane)*8 + t] = f2h_bits(w3.y);
        Bs[(14*64 + lane)*8 + t] = f2h_bits(w3.z);
        Bs[(15*64 + lane)*8 + t] = f2h_bits(w3.w);
        Bs[(16*64 + lane)*8 + t] = f2h_bits(W2[d * 16 + r]);
        float v;
        if (d < 16)       v = b1[r * 16 + d];
        else if (d == 16) v = b2[r];
        else              v = 0.0f;
        Bs[(17*64 + lane)*8 + t] = f2h_bits(v);
    }
    __syncthreads();   // only barrier in the kernel

    const int ntiles = (E + 15) >> 4;
    const int nwaves = (gridDim.x * blockDim.x) >> 6;
    const int wid    = (blockIdx.x * blockDim.x + threadIdx.x) >> 6;
    if (wid >= ntiles) return;

    const unsigned short* bsl = &Bs[lane * 8];   // per-lane base; block kk at +kk*512

#define LDSB(KK) __builtin_bit_cast(f16x8, *reinterpret_cast<const u32x4*>(bsl + (KK) * 512))

#define LOADT(T, E0, E1, H0, H1, H2, H3) { \
        int tt = (T); if (tt >= ntiles) tt = ntiles - 1; \
        int cc = tt * 16 + r; if (cc >= E) cc = E - 1; \
        const float4* ep_ = (const float4*)(eptr + (size_t)cc * 32 + g * 8); \
        E0 = ep_[0]; E1 = ep_[1]; \
        const float4* hp_ = (const float4*)(hptr + (size_t)cc * 16); \
        H0 = hp_[0]; H1 = hp_[1]; H2 = hp_[2]; H3 = hp_[3]; }

#define MB(HB, BF, ACC) { \
        const f16x2 hh_ = u2h(HB); \
        u32x4 u_ = {h2u(hh_ * u2h(eP0)), h2u(hh_ * u2h(eP1)), \
                    h2u(hh_ * u2h(eP2)), h2u(hh_ * u2h(eP3))}; \
        ACC = __builtin_amdgcn_mfma_f32_16x16x32_f16( \
            __builtin_bit_cast(f16x8, u_), BF, ACC, 0, 0, 0); }

    // BODY: Fb preload -> convert -> prefetch t+2 -> 18 MFMAs (rotated B) -> store
#define BODY(T, E0, E1, H0, H1, H2, H3) { \
        f16x8 Fb0 = LDSB(0), Fb1 = LDSB(1), Fb2 = LDSB(2), Fb3 = LDSB(3); \
        const unsigned int eP0 = pkrtz(E0.x, E0.y), eP1 = pkrtz(E0.z, E0.w); \
        const unsigned int eP2 = pkrtz(E1.x, E1.y), eP3 = pkrtz(E1.z, E1.w); \
        const unsigned int hB0  = pkrtz(H0.x, H0.x), hB1  = pkrtz(H0.y, H0.y); \
        const unsigned int hB2  = pkrtz(H0.z, H0.z), hB3  = pkrtz(H0.w, H0.w); \
        const unsigned int hB4  = pkrtz(H1.x, H1.x), hB5  = pkrtz(H1.y, H1.y); \
        const unsigned int hB6  = pkrtz(H1.z, H1.z), hB7  = pkrtz(H1.w, H1.w); \
        const unsigned int hB8  = pkrtz(H2.x, H2.x), hB9  = pkrtz(H2.y, H2.y); \
        const unsigned int hB10 = pkrtz(H2.z, H2.z), hB11 = pkrtz(H2.w, H2.w); \
        const unsigned int hB12 = pkrtz(H3.x, H3.x), hB13 = pkrtz(H3.y, H3.y); \
        const unsigned int hB14 = pkrtz(H3.z, H3.z), hB15 = pkrtz(H3.w, H3.w); \
        const float v0_ = (g == 0) ? H0.x : (g == 1) ? H2.x : (g == 2) ? 1.0f : 0.0f; \
        const float v1_ = (g == 0) ? H0.y : (g == 1) ? H2.y : 0.0f; \
        const float v2_ = (g == 0) ? H0.z : (g == 1) ? H2.z : 0.0f; \
        const float v3_ = (g == 0) ? H0.w : (g == 1) ? H2.w : 0.0f; \
        const float v4_ = (g == 0) ? H1.x : (g == 1) ? H3.x : 0.0f; \
        const float v5_ = (g == 0) ? H1.y : (g == 1) ? H3.y : 0.0f; \
        const float v6_ = (g == 0) ? H1.z : (g == 1) ? H3.z : 0.0f; \
        const float v7_ = (g == 0) ? H1.w : (g == 1) ? H3.w : 0.0f; \
        const unsigned int a17_0 = pkrtz(v0_, v1_), a17_1 = pkrtz(v2_, v3_); \
        const unsigned int a17_2 = pkrtz(v4_, v5_), a17_3 = pkrtz(v6_, v7_); \
        LOADT((T) + 2 * nwaves, E0, E1, H0, H1, H2, H3); \
        f32x4 acc0 = {0.0f, 0.0f, 0.0f, 0.0f}; \
        f32x4 acc1 = {0.0f, 0.0f, 0.0f, 0.0f}; \
        MB(hB0,  Fb0, acc0)  Fb0 = LDSB( 4); \
        MB(hB1,  Fb1, acc1)  Fb1 = LDSB( 5); \
        MB(hB2,  Fb2, acc0)  Fb2 = LDSB( 6); \
        MB(hB3,  Fb3, acc1)  Fb3 = LDSB( 7); \
        MB(hB4,  Fb0, acc0)  Fb0 = LDSB( 8); \
        MB(hB5,  Fb1, acc1)  Fb1 = LDSB( 9); \
        MB(hB6,  Fb2, acc0)  Fb2 = LDSB(10); \
        MB(hB7,  Fb3, acc1)  Fb3 = LDSB(11); \
        MB(hB8,  Fb0, acc0)  Fb0 = LDSB(12); \
        MB(hB9,  Fb1, acc1)  Fb1 = LDSB(13); \
        MB(hB10, Fb2, acc0)  Fb2 = LDSB(14); \
        MB(hB11, Fb3, acc1)  Fb3 = LDSB(15); \
        MB(hB12, Fb0, acc0)  Fb0 = LDSB(16); \
        MB(hB13, Fb1, acc1)  Fb1 = LDSB(17); \
        MB(hB14, Fb2, acc0) \
        MB(hB15, Fb3, acc1) \
        {   u32x4 u_ = {eP0, eP1, eP2, eP3};     /* block 16: A = e */ \
            acc0 = __builtin_amdgcn_mfma_f32_16x16x32_f16( \
                __builtin_bit_cast(f16x8, u_), Fb0, acc0, 0, 0, 0); } \
        {   u32x4 u_ = {a17_0, a17_1, a17_2, a17_3};  /* block 17 */ \
            acc1 = __builtin_amdgcn_mfma_f32_16x16x32_f16( \
                __builtin_bit_cast(f16x8, u_), Fb1, acc1, 0, 0, 0); } \
        const int rowbase_ = (T) * 16 + g * 4; \
        float* op_ = out + (size_t)rowbase_ * 16 + r; \
        const float s0_ = acc0[0] + acc1[0], s1_ = acc0[1] + acc1[1]; \
        const float s2_ = acc0[2] + acc1[2], s3_ = acc0[3] + acc1[3]; \
        if (rowbase_ + 3 < E) { op_[0] = s0_; op_[16] = s1_; op_[32] = s2_; op_[48] = s3_; } \
        else { \
            if (rowbase_     < E) op_[ 0] = s0_; \
            if (rowbase_ + 1 < E) op_[16] = s1_; \
            if (rowbase_ + 2 < E) op_[32] = s2_; \
        } }

    // ---- 2-deep pipeline, stages A/B alternate (all names static) ----
    float4 aE0, aE1, aH0, aH1, aH2, aH3;
    float4 bE0, bE1, bH0, bH1, bH2, bH3;

    int t = wid;
    LOADT(t,          aE0, aE1, aH0, aH1, aH2, aH3);
    LOADT(t + nwaves, bE0, bE1, bH0, bH1, bH2, bH3);

    while (true) {
        BODY(t, aE0, aE1, aH0, aH1, aH2, aH3);
        t += nwaves;
        if (t >= ntiles) break;
        BODY(t, bE0, bE1, bH0, bH1, bH2, bH3);
        t += nwaves;
        if (t >= ntiles) break;
    }

#undef BODY
#undef MB
#undef LOADT
#undef LDSB
}

extern "C" void kernel_launch(void* const* d_in, const int* in_sizes, int n_in,
                              void* d_out, int out_size, void* d_ws, size_t ws_size,
                              hipStream_t stream) {
    const float* h  = (const float*)d_in[0];
    const float* e  = (const float*)d_in[1];
    const float* W1 = (const float*)d_in[2];
    const float* b1 = (const float*)d_in[3];
    const float* W2 = (const float*)d_in[4];
    const float* b2 = (const float*)d_in[5];
    float* out = (float*)d_out;

    const int E = in_sizes[0] / 16;   // h is [E,16]

    dim3 grid(2048), block(256);
    hipLaunchKernelGGL(msg_kernel, grid, block, 0, stream,
                       h, e, W1, b1, W2, b2, out, E);
}

// Round 10
// 86.152 us; speedup vs baseline: 1.9491x; 1.0633x over previous
//
#include <hip/hip_runtime.h>
#include <hip/hip_bf16.h>

// out[e,i] = sum_j (e@W1+b1)[e, i*16+j] * h[e,j]  +  (e@W2+b2)[e,i]
// One fp16 MFMA GEMM over K=576 per 16-edge tile (18x mfma_f32_16x16x32_f16).
// K-mapping (same placement function on A and B sides):
//   main block kk=0..15, slot s=(lane>>4)*8+t:  (d=s, j=kk)
//     A[r,s] = e[edge_r, s] * h[edge_r, kk]     B[s, i=r] = W1[s*256 + r*16 + kk]
//   block 16: A = e[edge, s],                   B = W2[s*16 + r]
//   block 17: s<16: A=h[edge,s], B=b1[r*16+s]; s==16: A=1, B=b2[r]; else 0
//     -> per-lane A for block 17 is just hP0-3 (g=0), hP4-7 (g=1), {1,0..} (g=2), 0 (g=3)
// R9: VGPR diet targeting <=64 (m69: waves/SIMD step at 64/128/256 VGPR):
//   1-stage staging (24 f32), packed h pairs (8 u32) with op_sel broadcast at
//   use, free block-17 frag, Fb rotation depth 2. NO launch_bounds min-waves
//   (R7 spill lesson), NO local arrays (R2 PromoteAlloca lesson).

using f16x8  = __attribute__((ext_vector_type(8))) _Float16;
using f16x2  = __attribute__((ext_vector_type(2))) _Float16;
using fp16v2 = __attribute__((ext_vector_type(2))) __fp16;   // native cvt_pkrtz type
using f32x4  = __attribute__((ext_vector_type(4))) float;
using u32x4  = __attribute__((ext_vector_type(4))) unsigned int;

static __device__ __forceinline__ unsigned int pkrtz(float lo, float hi) {
    fp16v2 p = __builtin_amdgcn_cvt_pkrtz(lo, hi);
    return __builtin_bit_cast(unsigned int, p);
}
static __device__ __forceinline__ f16x2 u2h(unsigned int u) {
    return __builtin_bit_cast(f16x2, u);
}
static __device__ __forceinline__ unsigned int h2u(f16x2 h) {
    return __builtin_bit_cast(unsigned int, h);
}
static __device__ __forceinline__ unsigned short f2h_bits(float x) {
    _Float16 h = (_Float16)x;                 // RNE scalar cast (one-time build only)
    return __builtin_bit_cast(unsigned short, h);
}

__global__ void __launch_bounds__(256) msg_kernel(
    const float* __restrict__ hptr, const float* __restrict__ eptr,
    const float* __restrict__ W1,   const float* __restrict__ b1,
    const float* __restrict__ W2,   const float* __restrict__ b2,
    float* __restrict__ out, int E)
{
    // B fragment store: [kk=0..17][lane=0..63][t=0..7] fp16, 18 KB.
    __shared__ __align__(16) unsigned short Bs[18 * 64 * 8];

    const int lane = threadIdx.x & 63;
    const int g    = lane >> 4;        // K-group (0..3); lane's d-range = [g*8, g*8+8)
    const int r    = lane & 15;        // A row (edge-in-tile) == B/D col (output i)
    const int wv   = threadIdx.x >> 6; // wave id: parallel B-build by t-pair

    // ---- build B in LDS: wave wv handles t = wv*2, wv*2+1 ----
    #pragma unroll
    for (int tq = 0; tq < 2; ++tq) {
        const int t = wv * 2 + tq;
        const int d = g * 8 + t;
        const float4* wp = (const float4*)(W1 + (size_t)d * 256 + r * 16);
        const float4 w0 = wp[0], w1 = wp[1], w2 = wp[2], w3 = wp[3];
        Bs[( 0*64 + lane)*8 + t] = f2h_bits(w0.x);
        Bs[( 1*64 + lane)*8 + t] = f2h_bits(w0.y);
        Bs[( 2*64 + lane)*8 + t] = f2h_bits(w0.z);
        Bs[( 3*64 + lane)*8 + t] = f2h_bits(w0.w);
        Bs[( 4*64 + lane)*8 + t] = f2h_bits(w1.x);
        Bs[( 5*64 + lane)*8 + t] = f2h_bits(w1.y);
        Bs[( 6*64 + lane)*8 + t] = f2h_bits(w1.z);
        Bs[( 7*64 + lane)*8 + t] = f2h_bits(w1.w);
        Bs[( 8*64 + lane)*8 + t] = f2h_bits(w2.x);
        Bs[( 9*64 + lane)*8 + t] = f2h_bits(w2.y);
        Bs[(10*64 + lane)*8 + t] = f2h_bits(w2.z);
        Bs[(11*64 + lane)*8 + t] = f2h_bits(w2.w);
        Bs[(12*64 + lane)*8 + t] = f2h_bits(w3.x);
        Bs[(13*64 + lane)*8 + t] = f2h_bits(w3.y);
        Bs[(14*64 + lane)*8 + t] = f2h_bits(w3.z);
        Bs[(15*64 + lane)*8 + t] = f2h_bits(w3.w);
        Bs[(16*64 + lane)*8 + t] = f2h_bits(W2[d * 16 + r]);
        float v;
        if (d < 16)       v = b1[r * 16 + d];
        else if (d == 16) v = b2[r];
        else              v = 0.0f;
        Bs[(17*64 + lane)*8 + t] = f2h_bits(v);
    }
    __syncthreads();   // only barrier in the kernel

    const int ntiles = (E + 15) >> 4;
    const int nwaves = (gridDim.x * blockDim.x) >> 6;
    const int wid    = (blockIdx.x * blockDim.x + threadIdx.x) >> 6;
    if (wid >= ntiles) return;

    const unsigned short* bsl = &Bs[lane * 8];   // per-lane base; block kk at +kk*512

#define LDSB(KK) __builtin_bit_cast(f16x8, *reinterpret_cast<const u32x4*>(bsl + (KK) * 512))

#define LOADT(T, E0, E1, H0, H1, H2, H3) { \
        int tt = (T); if (tt >= ntiles) tt = ntiles - 1; \
        int cc = tt * 16 + r; if (cc >= E) cc = E - 1; \
        const float4* ep_ = (const float4*)(eptr + (size_t)cc * 32 + g * 8); \
        E0 = ep_[0]; E1 = ep_[1]; \
        const float4* hp_ = (const float4*)(hptr + (size_t)cc * 16); \
        H0 = hp_[0]; H1 = hp_[1]; H2 = hp_[2]; H3 = hp_[3]; }

    // MB: broadcast one fp16 from packed pair (static HALF -> VOP3P op_sel),
    // 4x v_pk_mul_f16, 1 MFMA with rotated B fragment.
#define MB(HPQ, HALF, BF, ACC) { \
        const f16x2 hv_ = u2h(HPQ); \
        const f16x2 hh_ = {hv_[HALF], hv_[HALF]}; \
        u32x4 u_ = {h2u(hh_ * u2h(eP0)), h2u(hh_ * u2h(eP1)), \
                    h2u(hh_ * u2h(eP2)), h2u(hh_ * u2h(eP3))}; \
        ACC = __builtin_amdgcn_mfma_f32_16x16x32_f16( \
            __builtin_bit_cast(f16x8, u_), BF, ACC, 0, 0, 0); }

    // ---- 1-stage pipeline ----
    float4 sE0, sE1, sH0, sH1, sH2, sH3;
    int t = wid;
    LOADT(t, sE0, sE1, sH0, sH1, sH2, sH3);

    while (true) {
        // B-frag preload (depth-2 rotation)
        f16x8 Fb0 = LDSB(0), Fb1 = LDSB(1);

        // convert staged f32 -> packed fp16 (waits on this tile's loads)
        const unsigned int eP0 = pkrtz(sE0.x, sE0.y), eP1 = pkrtz(sE0.z, sE0.w);
        const unsigned int eP2 = pkrtz(sE1.x, sE1.y), eP3 = pkrtz(sE1.z, sE1.w);
        const unsigned int hP0 = pkrtz(sH0.x, sH0.y), hP1 = pkrtz(sH0.z, sH0.w);
        const unsigned int hP2 = pkrtz(sH1.x, sH1.y), hP3 = pkrtz(sH1.z, sH1.w);
        const unsigned int hP4 = pkrtz(sH2.x, sH2.y), hP5 = pkrtz(sH2.z, sH2.w);
        const unsigned int hP6 = pkrtz(sH3.x, sH3.y), hP7 = pkrtz(sH3.z, sH3.w);

        // staging regs consumed -> immediately issue next tile's loads
        LOADT(t + nwaves, sE0, sE1, sH0, sH1, sH2, sH3);

        f32x4 acc0 = {0.0f, 0.0f, 0.0f, 0.0f};
        f32x4 acc1 = {0.0f, 0.0f, 0.0f, 0.0f};

        MB(hP0, 0, Fb0, acc0)  Fb0 = LDSB( 2);
        MB(hP0, 1, Fb1, acc1)  Fb1 = LDSB( 3);
        MB(hP1, 0, Fb0, acc0)  Fb0 = LDSB( 4);
        MB(hP1, 1, Fb1, acc1)  Fb1 = LDSB( 5);
        MB(hP2, 0, Fb0, acc0)  Fb0 = LDSB( 6);
        MB(hP2, 1, Fb1, acc1)  Fb1 = LDSB( 7);
        MB(hP3, 0, Fb0, acc0)  Fb0 = LDSB( 8);
        MB(hP3, 1, Fb1, acc1)  Fb1 = LDSB( 9);
        MB(hP4, 0, Fb0, acc0)  Fb0 = LDSB(10);
        MB(hP4, 1, Fb1, acc1)  Fb1 = LDSB(11);
        MB(hP5, 0, Fb0, acc0)  Fb0 = LDSB(12);
        MB(hP5, 1, Fb1, acc1)  Fb1 = LDSB(13);
        MB(hP6, 0, Fb0, acc0)  Fb0 = LDSB(14);
        MB(hP6, 1, Fb1, acc1)  Fb1 = LDSB(15);
        MB(hP7, 0, Fb0, acc0)  Fb0 = LDSB(16);
        MB(hP7, 1, Fb1, acc1)  Fb1 = LDSB(17);

        {   // block 16: A = packed e
            u32x4 u_ = {eP0, eP1, eP2, eP3};
            acc0 = __builtin_amdgcn_mfma_f32_16x16x32_f16(
                __builtin_bit_cast(f16x8, u_), Fb0, acc0, 0, 0, 0);
        }
        {   // block 17: A = hP0-3 (g=0) / hP4-7 (g=1) / {1,0,..} (g=2) / 0 (g=3)
            const unsigned int a0 = (g == 0) ? hP0 : (g == 1) ? hP4
                                   : (g == 2) ? 0x00003C00u : 0u;
            const unsigned int a1 = (g == 0) ? hP1 : (g == 1) ? hP5 : 0u;
            const unsigned int a2 = (g == 0) ? hP2 : (g == 1) ? hP6 : 0u;
            const unsigned int a3 = (g == 0) ? hP3 : (g == 1) ? hP7 : 0u;
            u32x4 u_ = {a0, a1, a2, a3};
            acc1 = __builtin_amdgcn_mfma_f32_16x16x32_f16(
                __builtin_bit_cast(f16x8, u_), Fb1, acc1, 0, 0, 0);
        }

        // D: col = r = i, row = g*4 + q = edge-in-tile
        const int rowbase = t * 16 + g * 4;
        float* op = out + (size_t)rowbase * 16 + r;
        const float s0 = acc0[0] + acc1[0], s1 = acc0[1] + acc1[1];
        const float s2 = acc0[2] + acc1[2], s3 = acc0[3] + acc1[3];
        if (rowbase + 3 < E) { op[0] = s0; op[16] = s1; op[32] = s2; op[48] = s3; }
        else {
            if (rowbase     < E) op[ 0] = s0;
            if (rowbase + 1 < E) op[16] = s1;
            if (rowbase + 2 < E) op[32] = s2;
        }

        t += nwaves;
        if (t >= ntiles) break;
    }

#undef MB
#undef LOADT
#undef LDSB
}

extern "C" void kernel_launch(void* const* d_in, const int* in_sizes, int n_in,
                              void* d_out, int out_size, void* d_ws, size_t ws_size,
                              hipStream_t stream) {
    const float* h  = (const float*)d_in[0];
    const float* e  = (const float*)d_in[1];
    const float* W1 = (const float*)d_in[2];
    const float* b1 = (const float*)d_in[3];
    const float* W2 = (const float*)d_in[4];
    const float* b2 = (const float*)d_in[5];
    float* out = (float*)d_out;

    const int E = in_sizes[0] / 16;   // h is [E,16]

    dim3 grid(2048), block(256);
    hipLaunchKernelGGL(msg_kernel, grid, block, 0, stream,
                       h, e, W1, b1, W2, b2, out, E);
}